// Round 8
// baseline (329.653 us; speedup 1.0000x reference)
//
#include <hip/hip_runtime.h>
#include <cstdint>

// ---------------------------------------------------------------------------
// minerva_transform: logits = (l2(Xe) @ l2(De)^T)^3 @ rh ; preds = sigmoid
// R8: 2 dispatches (per-dispatch overhead measured ~15us).
//   1) k_embed: fp32 X/D/g_w direct, REGISTER-PREFETCH staging for cold A
//      (loads for iter k+1 issued after barrier-2, overlap compute), B inline
//      (L2-hot), XCD-co-located grid, Eb bf16 + norm2p slots; pad blocks
//      zero lg.
//   2) k_minerva: R7-verified GEMM (BK=64, XOR-swizzled LDS, panel W=20
//      m-fast), lg via device-scope atomicAdd (R3-proven), last-done-block
//      finalize with self-resetting counter + agent-scope atomic loads.
// ---------------------------------------------------------------------------

typedef __attribute__((ext_vector_type(4))) float  f32x4;
typedef __attribute__((ext_vector_type(8))) __bf16 bf16x8;

constexpr int B = 4096, N = 20000, F = 768, E = 512;
constexpr int NROWS = 24576;   // padded g-rows (192 row-tiles)
constexpr int NT = 157, MT = 32, W = 20;
constexpr unsigned MINERVA_BLOCKS = (unsigned)(NT * MT);   // 5024

#define AS1CAST(p) ((__attribute__((address_space(1))) unsigned int*)(uintptr_t)(p))
#define AS3CAST(p) ((__attribute__((address_space(3))) unsigned int*)(uintptr_t)(p))

__device__ __forceinline__ void gload_lds16(const void* g, void* l) {
  __builtin_amdgcn_global_load_lds(AS1CAST(g), AS3CAST(l), 16, 0, 0);
}

__device__ unsigned g_done = 0;   // self-resetting across launches/replays

__device__ __forceinline__ bf16x8 cvt2(const float4 v0, const float4 v1) {
  bf16x8 t;
  t[0] = (__bf16)v0.x; t[1] = (__bf16)v0.y; t[2] = (__bf16)v0.z; t[3] = (__bf16)v0.w;
  t[4] = (__bf16)v1.x; t[5] = (__bf16)v1.y; t[6] = (__bf16)v1.z; t[7] = (__bf16)v1.w;
  return t;
}

// ------------------------- embedding GEMM (fp32 in) ------------------------
// bid = bx*192 + by : by = row-tile (0..31 X, 32..188 D, 189..191 pad),
// bx = e-tile.  4 bx-blocks of one by differ by 192 = 0 mod 8 -> same XCD.
// A (cold HBM) staged via register-prefetch dbuf; B=G (L2-hot) inline.

__global__ __launch_bounds__(256, 3)
void k_embed(const float* __restrict__ X, const float* __restrict__ D,
             const float* __restrict__ G, const float* __restrict__ bias,
             __bf16* __restrict__ Eb, float* __restrict__ norm2p,
             float* __restrict__ lg) {
  __shared__ __bf16 As[128 * 64];
  __shared__ __bf16 Bs[128 * 64];
  __shared__ float lsum[128];
  const int tid  = threadIdx.x;
  const int bid  = blockIdx.x;
  const int wave = tid >> 6;
  const int lane = tid & 63;
  const int bx = bid / 192;     // e-tile 0..3
  const int by = bid % 192;     // row-tile (XCD-pinned: by&7)

  if (by >= 189) {              // pad blocks: one zeroes lg, rest exit
    if (bx == 0 && by == 189)
      for (int i = tid; i < B; i += 256) lg[i] = 0.0f;
    return;
  }

  const bool isX = (by < 32);
  const float* A = isX ? X : D;
  const int m0 = isX ? by * 128 : (by - 32) * 128;
  const int Mr = isX ? B : N;
  const int g0 = by * 128;
  const int n0 = bx * 128;
  if (tid < 128) lsum[tid] = 0.0f;

  // staging: thread t -> rows rbase+32q, colgrp cg (8 fp32 = 2 float4),
  // stored at swizzled slot cg^(row&7)
  const int cg    = tid & 7;
  const int rbase = tid >> 3;
  const int sw    = (cg ^ (rbase & 7)) * 8;
  size_t aoff[4], boff[4];
  int    lidx[4];
#pragma unroll
  for (int q = 0; q < 4; ++q) {
    const int rt = rbase + 32 * q;
    int arow = m0 + rt; if (arow >= Mr) arow = Mr - 1;
    aoff[q] = (size_t)arow * F + cg * 8;
    boff[q] = (size_t)(n0 + rt) * F + cg * 8;
    lidx[q] = rt * 64 + sw;
  }

  const int mw = (wave & 1) * 64;
  const int nw = (wave >> 1) * 64;
  const int quad = lane >> 4;
  const int l15  = lane & 15;
  f32x4 acc[4][4] = {};

  // preload A tile 0 into registers
  float4 a0[4], a1[4];
#pragma unroll
  for (int q = 0; q < 4; ++q) {
    a0[q] = *(const float4*)(A + aoff[q]);
    a1[q] = *(const float4*)(A + aoff[q] + 4);
  }

  for (int kb = 0; kb < F; kb += 64) {
    __syncthreads();   // LDS free (prev compute done); drains A prefetch
    // A: write prefetched regs -> LDS
#pragma unroll
    for (int q = 0; q < 4; ++q)
      *(bf16x8*)&As[lidx[q]] = cvt2(a0[q], a1[q]);
    // B: inline (L2-hot after first row-tile per XCD)
#pragma unroll
    for (int q = 0; q < 4; ++q) {
      const float4 v0 = *(const float4*)(G + boff[q] + kb);
      const float4 v1 = *(const float4*)(G + boff[q] + kb + 4);
      *(bf16x8*)&Bs[lidx[q]] = cvt2(v0, v1);
    }
    __syncthreads();
    // issue next A loads AFTER barrier -> overlap with compute below
    if (kb + 64 < F) {
#pragma unroll
      for (int q = 0; q < 4; ++q) {
        a0[q] = *(const float4*)(A + aoff[q] + kb + 64);
        a1[q] = *(const float4*)(A + aoff[q] + kb + 68);
      }
    }
#pragma unroll
    for (int h = 0; h < 2; ++h) {
      bf16x8 af[4], bfr[4];
#pragma unroll
      for (int i = 0; i < 4; ++i) {
        const int rr = mw + i * 16 + l15;
        af[i] = *(const bf16x8*)&As[rr * 64 + ((quad + h * 4) ^ (rr & 7)) * 8];
      }
#pragma unroll
      for (int j = 0; j < 4; ++j) {
        const int rr = nw + j * 16 + l15;
        bfr[j] = *(const bf16x8*)&Bs[rr * 64 + ((quad + h * 4) ^ (rr & 7)) * 8];
      }
#pragma unroll
      for (int i = 0; i < 4; ++i)
#pragma unroll
        for (int j = 0; j < 4; ++j)
          acc[i][j] = __builtin_amdgcn_mfma_f32_16x16x32_bf16(af[i], bfr[j], acc[i][j], 0, 0, 0);
    }
  }

  // epilogue: bf16 store + row sum-of-squares (C/D: col=l15, row=quad*4+rr)
#pragma unroll
  for (int i = 0; i < 4; ++i) {
    float part[4] = {0.0f, 0.0f, 0.0f, 0.0f};
#pragma unroll
    for (int j = 0; j < 4; ++j) {
      const int col = n0 + nw + j * 16 + l15;
      const float bv = bias[col];
#pragma unroll
      for (int rr = 0; rr < 4; ++rr) {
        const int row = mw + i * 16 + quad * 4 + rr;
        if (m0 + row < Mr) {
          const __bf16 hv = (__bf16)(acc[i][j][rr] + bv);
          Eb[(size_t)(g0 + row) * E + col] = hv;
          const float vb = (float)hv;
          part[rr] += vb * vb;
        }
      }
    }
#pragma unroll
    for (int rr = 0; rr < 4; ++rr) {
      float v = part[rr];
      v += __shfl_xor(v, 1);
      v += __shfl_xor(v, 2);
      v += __shfl_xor(v, 4);
      v += __shfl_xor(v, 8);
      if (l15 == 0) atomicAdd(&lsum[mw + i * 16 + quad * 4 + rr], v);  // LDS only
    }
  }
  __syncthreads();
  if (tid < 128) norm2p[(size_t)bx * NROWS + g0 + tid] = lsum[tid];  // race-free slot
}

// ------------------------- fused Minerva GEMM + finalize -------------------
// R7-verified GEMM; logits via device-scope atomicAdd (coherent point);
// last-done-block computes sigmoid (agent-scope atomic loads of lg).

__global__ __launch_bounds__(256, 3)
void k_minerva(const __bf16* __restrict__ Eb, const float* __restrict__ norm2p,
               const float* __restrict__ r, const float* __restrict__ hw,
               const float* __restrict__ hb, float* __restrict__ lg,
               float* __restrict__ out) {
  __shared__ __bf16 As[128 * 64];
  __shared__ __bf16 Bs[128 * 64];
  __shared__ float lsum[128];
  __shared__ int amLast;
  const int tid  = threadIdx.x;
  const int lane = tid & 63;
  const int wave = tid >> 6;

  // panel decomposition, m-fast within W=20 n-tile panels
  const int bid   = blockIdx.x;
  const int panel = bid / (W * MT);
  const int bn    = panel * W;
  const int rem   = bid - panel * (W * MT);
  const int mt    = rem % MT;
  const int nt    = bn + rem / MT;
  const int m0 = mt * 128, n0 = nt * 128;
  if (tid < 128) lsum[tid] = 0.0f;

  const __bf16* Xe = Eb;
  const __bf16* De = Eb + (size_t)B * E;
  const int srow = tid >> 3;
  const int scg  = (tid & 7) ^ (srow & 7);
  const __bf16* ga[4]; const __bf16* gb[4]; int li[4];
#pragma unroll
  for (int q = 0; q < 4; ++q) {
    const int row = srow + 32 * q;
    const int arow = m0 + row;                     // < 4096 always
    int brow = n0 + row; if (brow >= N) brow = N - 1;
    ga[q] = Xe + (size_t)arow * E + scg * 8;
    gb[q] = De + (size_t)brow * E + scg * 8;
    li[q] = q * 2048 + tid * 8;
  }

  const int mw = (wave & 1) * 64;
  const int nw = (wave >> 1) * 64;
  const int quad = lane >> 4;
  const int l15  = lane & 15;
  f32x4 acc[4][4] = {};

  for (int kb = 0; kb < E; kb += 64) {
#pragma unroll
    for (int q = 0; q < 4; ++q) gload_lds16(ga[q] + kb, &As[li[q]]);
#pragma unroll
    for (int q = 0; q < 4; ++q) gload_lds16(gb[q] + kb, &Bs[li[q]]);
    __syncthreads();
#pragma unroll
    for (int h = 0; h < 2; ++h) {
      bf16x8 af[4], bfr[4];
#pragma unroll
      for (int i = 0; i < 4; ++i) {
        const int rr = mw + i * 16 + l15;
        af[i] = *(const bf16x8*)&As[rr * 64 + ((quad + h * 4) ^ (rr & 7)) * 8];
      }
#pragma unroll
      for (int j = 0; j < 4; ++j) {
        const int rr = nw + j * 16 + l15;
        bfr[j] = *(const bf16x8*)&Bs[rr * 64 + ((quad + h * 4) ^ (rr & 7)) * 8];
      }
#pragma unroll
      for (int i = 0; i < 4; ++i)
#pragma unroll
        for (int j = 0; j < 4; ++j)
          acc[i][j] = __builtin_amdgcn_mfma_f32_16x16x32_bf16(af[i], bfr[j], acc[i][j], 0, 0, 0);
    }
    __syncthreads();
  }

  // epilogue: s^3*rh = acc^3 * ix^3 * (id^3*rh);  rh inline from r
  const float hwv = hw[0], hbv = hb[0];
  float id3rh[4];
#pragma unroll
  for (int j = 0; j < 4; ++j) {
    const int col = n0 + nw + j * 16 + l15;
    if (col < N) {
      const int gr = B + col;
      const float nd2 = norm2p[gr] + norm2p[NROWS + gr]
                      + norm2p[2 * NROWS + gr] + norm2p[3 * NROWS + gr];
      const float id = 1.0f / fmaxf(sqrtf(nd2), 1e-12f);
      const float rhv = (2.0f * r[col] - 1.0f) * hwv + hbv;
      id3rh[j] = id * id * id * rhv;
    } else id3rh[j] = 0.0f;   // kills padded/clamped cols
  }
#pragma unroll
  for (int i = 0; i < 4; ++i) {
    const int rowb = m0 + mw + i * 16 + quad * 4;
    const float4 s0 = *(const float4*)(norm2p + rowb);
    const float4 s1 = *(const float4*)(norm2p + NROWS + rowb);
    const float4 s2 = *(const float4*)(norm2p + 2 * NROWS + rowb);
    const float4 s3 = *(const float4*)(norm2p + 3 * NROWS + rowb);
    const float nx2[4] = { s0.x + s1.x + s2.x + s3.x, s0.y + s1.y + s2.y + s3.y,
                           s0.z + s1.z + s2.z + s3.z, s0.w + s1.w + s2.w + s3.w };
    float part[4] = {0.0f, 0.0f, 0.0f, 0.0f};
#pragma unroll
    for (int j = 0; j < 4; ++j)
#pragma unroll
      for (int rr = 0; rr < 4; ++rr) {
        const float a = acc[i][j][rr];
        part[rr] = fmaf(a * a * a, id3rh[j], part[rr]);
      }
#pragma unroll
    for (int rr = 0; rr < 4; ++rr) {
      const float ix = 1.0f / fmaxf(sqrtf(nx2[rr]), 1e-12f);
      float v = part[rr] * (ix * ix * ix);
      v += __shfl_xor(v, 1);
      v += __shfl_xor(v, 2);
      v += __shfl_xor(v, 4);
      v += __shfl_xor(v, 8);
      if (l15 == 0) atomicAdd(&lsum[mw + i * 16 + quad * 4 + rr], v);  // LDS only
    }
  }
  __syncthreads();
  if (tid < 128) atomicAdd(&lg[m0 + tid], lsum[tid]);   // device-scope, coherent

  // ---- last-done-block finalize ----
  __syncthreads();   // drains this block's vmcnt -> its lg atomics performed
  if (tid == 0) {
    const unsigned prev =
        __hip_atomic_fetch_add(&g_done, 1u, __ATOMIC_ACQ_REL, __HIP_MEMORY_SCOPE_AGENT);
    amLast = (prev == MINERVA_BLOCKS - 1u);
    if (amLast)
      __hip_atomic_store(&g_done, 0u, __ATOMIC_RELAXED, __HIP_MEMORY_SCOPE_AGENT);
  }
  __syncthreads();
  if (amLast) {
    for (int i = tid; i < B; i += 256) {
      // agent-scope atomic load: reads coherent point (all atomicAdds visible)
      const float L = __hip_atomic_load(&lg[i], __ATOMIC_RELAXED, __HIP_MEMORY_SCOPE_AGENT);
      out[i] = L;
      out[B + i] = 1.0f / (1.0f + expf(-L));
    }
  }
}

// ------------------------- launcher ----------------------------------------

extern "C" void kernel_launch(void* const* d_in, const int* in_sizes, int n_in,
                              void* d_out, int out_size, void* d_ws, size_t ws_size,
                              hipStream_t stream) {
  const float* X   = (const float*)d_in[0];
  const float* D   = (const float*)d_in[1];
  const float* r   = (const float*)d_in[2];
  const float* g_w = (const float*)d_in[3];
  const float* g_b = (const float*)d_in[4];
  const float* h_w = (const float*)d_in[5];
  const float* h_b = (const float*)d_in[6];
  float* out = (float*)d_out;

  // ws layout (bytes), 256-aligned, total ~25.1 MB
  char* ws = (char*)d_ws;
  __bf16* Eb     = (__bf16*)(ws + 0);          // 24096*512*2 = 24,674,304
  float*  norm2p = (float*) (ws + 24674304);   // 4*24576*4  =    393,216
  float*  lg     = (float*) (ws + 25067520);   // 4096*4     =     16,384

  // 1. embedding GEMM straight from fp32 inputs (+ lg zeroing by pad block)
  k_embed<<<4 * 192, 256, 0, stream>>>(X, D, g_w, g_b, Eb, norm2p, lg);

  // 2. cosine^3-weighted retrieval + last-done-block finalize
  k_minerva<<<MINERVA_BLOCKS, 256, 0, stream>>>(Eb, norm2p, r, h_w, h_b, lg, out);
}